// Round 1
// 3300.095 us; speedup vs baseline: 1.6215x; 1.6215x over previous
//
#include <hip/hip_runtime.h>

#define N_TOK 524288
#define DIM 128
#define NCODE 512
#define TAU 5e-5f

#define MTILE 32            // tokens per block
#define KT 8                // k-slice per staged emb tile
#define NTILES (DIM / KT)   // 16

// ws layout: [0,8) double loss_acc | [8,12) int cnt | [16,...) int list[cap]

// numpy-pairwise-style fp32 sum of 128 squares: 8 accumulators stride 8,
// separate mul/add rounding, combined ((r0+r1)+(r2+r3))+((r4+r5)+(r6+r7)).
__device__ __forceinline__ float np_sumsq128(const float* __restrict__ p) {
#pragma clang fp contract(off)
    float r[8];
#pragma unroll
    for (int j = 0; j < 8; ++j) { float v = p[j]; r[j] = v * v; }
#pragma unroll
    for (int i = 8; i < 128; i += 8) {
#pragma unroll
        for (int j = 0; j < 8; ++j) { float v = p[i + j]; r[j] = r[j] + v * v; }
    }
    return ((r[0] + r[1]) + (r[2] + r[3])) + ((r[4] + r[5]) + (r[6] + r[7]));
}

// sgemm-style fp32 dot: sequential FMA chain in natural order.
__device__ __forceinline__ float seq_dot128(const float* __restrict__ a,
                                            const float* __restrict__ b) {
    float acc = 0.f;
#pragma unroll
    for (int d = 0; d < DIM; ++d) acc = __builtin_fmaf(a[d], b[d], acc);
    return acc;
}

// Full numpy-fp32 emulation of argmin over all codes for one token (scalar).
// Cold path -- keep out of the hot kernel's register budget.
__device__ __attribute__((noinline)) int np_argmin_token(
    const float* __restrict__ zrow, const float* __restrict__ emb) {
    float zn = np_sumsq128(zrow);
    float bd = 1e30f; int bk = 0;
    for (int k = 0; k < NCODE; ++k) {
        const float* e = emb + (size_t)k * DIM;
        float en = np_sumsq128(e);
        float dot = seq_dot128(zrow, e);
        float t = zn + en;           // fp32 add (grid ~1.5e-5 at 128)
        float c = t - 2.0f * dot;    // 2*dot exact; single fp32 rounding
        if (c < bd) { bd = c; bk = k; }  // strict < = np first-occurrence
    }
    return bk;
}

__global__ void vq_prep(double* loss_acc, int* cnt) {
    *loss_acc = 0.0;
    *cnt = 0;
}

#define FMA4(AV, B, ACC)                                   \
    ACC.x = fmaf(AV, B.x, ACC.x); ACC.y = fmaf(AV, B.y, ACC.y); \
    ACC.z = fmaf(AV, B.z, ACC.z); ACC.w = fmaf(AV, B.w, ACC.w);

__global__ __launch_bounds__(256) void vq_main(
    const float* __restrict__ z, const float* __restrict__ emb,
    float* __restrict__ out_q, float* __restrict__ out_idx,
    double* __restrict__ loss_acc, int* __restrict__ cnt,
    int* __restrict__ list, int cap)
{
    // LDS: 16KB z-tile + 2x16KB emb double-buffer (transposed) + 2KB norms = 50KB
    __shared__ __align__(16) float s_z[MTILE * DIM];        // [m][k]
    __shared__ __align__(16) float s_b[2][KT][NCODE];       // [k][n]
    __shared__ float s_enorm[NCODE];

    const int tid = threadIdx.x;
    const int w = tid >> 6;          // wave id: owns tokens m0..m0+7
    const int l = tid & 63;          // lane: owns codes 4l..4l+3, 256+4l..+3
    const int m0 = w * 8;
    const size_t blockRow = (size_t)blockIdx.x * MTILE;

    s_enorm[tid] = 0.f;
    s_enorm[tid + 256] = 0.f;

    // stage z tile (coalesced float4, linear LDS writes)
    {
        const float4* zg = (const float4*)(z + blockRow * DIM);
        float4* zs = (float4*)s_z;
#pragma unroll
        for (int i = 0; i < 4; ++i) { int f = i * 256 + tid; zs[f] = zg[f]; }
    }

    // B staging piece map: p = i*256+tid -> code n = p&511, k-half kh = p>>9
    float4 v[4];
#pragma unroll
    for (int i = 0; i < 4; ++i) {
        int p = i * 256 + tid;
        int n = p & (NCODE - 1);
        int kh = p >> 9;
        v[i] = *(const float4*)(emb + (size_t)n * DIM + kh * 4);
    }
    __syncthreads();  // s_z + enorm init visible

    // write tile 0 (transpose scatter; lane-consecutive n => conflict-free)
#pragma unroll
    for (int i = 0; i < 4; ++i) {
        int p = i * 256 + tid;
        int n = p & (NCODE - 1);
        int kh = p >> 9;
        float4 t = v[i];
        s_b[0][kh * 4 + 0][n] = t.x; s_b[0][kh * 4 + 1][n] = t.y;
        s_b[0][kh * 4 + 2][n] = t.z; s_b[0][kh * 4 + 3][n] = t.w;
        atomicAdd(&s_enorm[n], (t.x * t.x + t.y * t.y) + (t.z * t.z + t.w * t.w));
    }
    __syncthreads();

    float4 acc0[8], acc1[8];
#pragma unroll
    for (int i = 0; i < 8; ++i) {
        acc0[i] = float4{0.f, 0.f, 0.f, 0.f};
        acc1[i] = float4{0.f, 0.f, 0.f, 0.f};
    }

    for (int t = 0; t < NTILES; ++t) {
        const int buf = t & 1;
        // issue next tile's global loads early (L2 latency hides under compute)
        if (t + 1 < NTILES) {
#pragma unroll
            for (int i = 0; i < 4; ++i) {
                int p = i * 256 + tid;
                int n = p & (NCODE - 1);
                int kh = p >> 9;
                v[i] = *(const float4*)(emb + (size_t)n * DIM + (t + 1) * KT + kh * 4);
            }
        }
        // compute: two 4-k chunks; per-acc FMA order is k-ascending =>
        // dot chain is bit-identical to seq_dot128 (np emulation path).
#pragma unroll
        for (int c = 0; c < 2; ++c) {
            float4 a[8];
#pragma unroll
            for (int i = 0; i < 8; ++i)
                a[i] = *(const float4*)&s_z[(m0 + i) * DIM + t * KT + c * 4];
            float4 b0[4], b1[4];
#pragma unroll
            for (int kk = 0; kk < 4; ++kk) {
                b0[kk] = *(const float4*)&s_b[buf][c * 4 + kk][4 * l];
                b1[kk] = *(const float4*)&s_b[buf][c * 4 + kk][NCODE / 2 + 4 * l];
            }
#pragma unroll
            for (int i = 0; i < 8; ++i) {
                FMA4(a[i].x, b0[0], acc0[i])
                FMA4(a[i].y, b0[1], acc0[i])
                FMA4(a[i].z, b0[2], acc0[i])
                FMA4(a[i].w, b0[3], acc0[i])
                FMA4(a[i].x, b1[0], acc1[i])
                FMA4(a[i].y, b1[1], acc1[i])
                FMA4(a[i].z, b1[2], acc1[i])
                FMA4(a[i].w, b1[3], acc1[i])
            }
        }
        // write next tile into the other buffer (safe: everyone finished
        // reading it before the barrier that ended the previous iteration)
        if (t + 1 < NTILES) {
#pragma unroll
            for (int i = 0; i < 4; ++i) {
                int p = i * 256 + tid;
                int n = p & (NCODE - 1);
                int kh = p >> 9;
                float4 tv = v[i];
                s_b[buf ^ 1][kh * 4 + 0][n] = tv.x;
                s_b[buf ^ 1][kh * 4 + 1][n] = tv.y;
                s_b[buf ^ 1][kh * 4 + 2][n] = tv.z;
                s_b[buf ^ 1][kh * 4 + 3][n] = tv.w;
                atomicAdd(&s_enorm[n],
                          (tv.x * tv.x + tv.y * tv.y) + (tv.z * tv.z + tv.w * tv.w));
            }
        }
        __syncthreads();
    }

    // ---- fused argmin epilogue ----
    float4 en0 = *(const float4*)&s_enorm[4 * l];
    float4 en1 = *(const float4*)&s_enorm[NCODE / 2 + 4 * l];

    float my1 = 0.f, my2 = 0.f; int myk = 0;

#define UPD(DV, KV)                                              \
    { float d_ = (DV);                                           \
      if (d_ < m1) { m2 = m1; m1 = d_; bk = (KV); }              \
      else if (d_ < m2) { m2 = d_; } }

#pragma unroll
    for (int i = 0; i < 8; ++i) {
        float m1 = 1e30f, m2 = 1e30f; int bk = 0;
        // lane-local scan in ascending code order (first-occurrence semantics)
        UPD(fmaf(-2.f, acc0[i].x, en0.x), 4 * l + 0)
        UPD(fmaf(-2.f, acc0[i].y, en0.y), 4 * l + 1)
        UPD(fmaf(-2.f, acc0[i].z, en0.z), 4 * l + 2)
        UPD(fmaf(-2.f, acc0[i].w, en0.w), 4 * l + 3)
        UPD(fmaf(-2.f, acc1[i].x, en1.x), NCODE / 2 + 4 * l + 0)
        UPD(fmaf(-2.f, acc1[i].y, en1.y), NCODE / 2 + 4 * l + 1)
        UPD(fmaf(-2.f, acc1[i].z, en1.z), NCODE / 2 + 4 * l + 2)
        UPD(fmaf(-2.f, acc1[i].w, en1.w), NCODE / 2 + 4 * l + 3)
        // 64-lane butterfly carrying (m1, m2, best-k) with lowest-k tie-break
#pragma unroll
        for (int off = 1; off < 64; off <<= 1) {
            float b1 = __shfl_xor(m1, off);
            float b2 = __shfl_xor(m2, off);
            int   bko = __shfl_xor(bk, off);
            float nm2 = fminf(fminf(m2, b2), fmaxf(m1, b1));
            if (b1 < m1 || (b1 == m1 && bko < bk)) { m1 = b1; bk = bko; }
            m2 = nm2;
        }
        if (l == i) { my1 = m1; my2 = m2; myk = bk; }
    }

    // owner lane per token: TAU guard + proven epilogue tail
    double sd = 0.0;
    if (l < 8) {
        size_t n = blockRow + (size_t)(m0 + l);
        int best = myk;
        if (my2 - my1 < TAU) {
            int pos = atomicAdd(cnt, 1);
            if (pos < cap) {
                list[pos] = (int)n;      // refined by vq_refine
            } else {
                best = np_argmin_token(z + n * DIM, emb);  // cold fallback
            }
        }
        const float4* eb = (const float4*)(emb + (size_t)best * DIM);
        const float4* zr4 = (const float4*)&s_z[(m0 + l) * DIM];
        float4* oq = (float4*)(out_q + n * DIM);
        float sx = 0.f, sy = 0.f, szz = 0.f, sw = 0.f;
#pragma unroll
        for (int j = 0; j < DIM / 4; ++j) {
            float4 e = eb[j];
            float4 zz = zr4[j];
            float dx = e.x - zz.x, dy = e.y - zz.y, dz = e.z - zz.z, dw = e.w - zz.w;
            float4 o; o.x = zz.x + dx; o.y = zz.y + dy; o.z = zz.z + dz; o.w = zz.w + dw;
            oq[j] = o;
            sx = fmaf(dx, dx, sx); sy = fmaf(dy, dy, sy);
            szz = fmaf(dz, dz, szz); sw = fmaf(dw, dw, sw);
        }
        out_idx[n] = (float)best;
        sd = (double)((sx + sy) + (szz + sw));
    }
#pragma unroll
    for (int off = 32; off > 0; off >>= 1) sd += __shfl_down(sd, off);
    if (l == 0 && sd != 0.0) atomicAdd(loss_acc, sd);
}

// One block per ambiguous token; numpy-fp32 emulated distances; block argmin
// with first-occurrence (lowest k) tie-break.
__global__ __launch_bounds__(256) void vq_refine(
    const float* __restrict__ z, const float* __restrict__ emb,
    float* __restrict__ out_q, float* __restrict__ out_idx,
    const int* __restrict__ cnt, const int* __restrict__ list, int cap)
{
    __shared__ float s_zr[DIM];
    __shared__ float s_d[256];
    __shared__ int s_k[256];
    int nwork = *cnt;
    if (nwork > cap) nwork = cap;
    for (int i = blockIdx.x; i < nwork; i += gridDim.x) {
        int n = list[i];
        if (threadIdx.x < DIM) s_zr[threadIdx.x] = z[(size_t)n * DIM + threadIdx.x];
        __syncthreads();

        float zn = np_sumsq128(s_zr);  // identical across threads (same order)
        float bd = 1e30f; int bk = 1 << 30;
#pragma unroll
        for (int t = 0; t < NCODE / 256; ++t) {
            int k = threadIdx.x + 256 * t;
            const float* e = emb + (size_t)k * DIM;
            float en = np_sumsq128(e);
            float dot = seq_dot128(s_zr, e);
            float tt = zn + en;
            float c = tt - 2.0f * dot;
            if (c < bd || (c == bd && k < bk)) { bd = c; bk = k; }
        }
        s_d[threadIdx.x] = bd;
        s_k[threadIdx.x] = bk;
        __syncthreads();
        for (int s = 128; s > 0; s >>= 1) {
            if (threadIdx.x < s) {
                float od = s_d[threadIdx.x + s];
                int ok = s_k[threadIdx.x + s];
                if (od < s_d[threadIdx.x] ||
                    (od == s_d[threadIdx.x] && ok < s_k[threadIdx.x])) {
                    s_d[threadIdx.x] = od;
                    s_k[threadIdx.x] = ok;
                }
            }
            __syncthreads();
        }
        int best = s_k[0];

        if (threadIdx.x < DIM) {
            float e = emb[(size_t)best * DIM + threadIdx.x];
            float zz = s_zr[threadIdx.x];
            out_q[(size_t)n * DIM + threadIdx.x] = zz + (e - zz);
        }
        if (threadIdx.x == 0) out_idx[n] = (float)best;
        __syncthreads();
    }
}

__global__ void vq_final(const double* __restrict__ loss_acc, float* __restrict__ out_loss) {
    double m = *loss_acc / ((double)N_TOK * (double)DIM);
    *out_loss = (float)(1.25 * m);  // q_latent + 0.25 * e_latent (equal values)
}

extern "C" void kernel_launch(void* const* d_in, const int* in_sizes, int n_in,
                              void* d_out, int out_size, void* d_ws, size_t ws_size,
                              hipStream_t stream) {
    const float* z = (const float*)d_in[0];
    const float* emb = (const float*)d_in[1];
    float* out_q = (float*)d_out;
    float* out_loss = out_q + (size_t)N_TOK * DIM;
    float* out_idx = out_loss + 1;

    char* ws = (char*)d_ws;
    double* loss_acc = (double*)ws;
    int* cnt = (int*)(ws + 8);
    int* list = (int*)(ws + 16);
    long cap_l = ((long)ws_size - 16) / 4;
    if (cap_l < 0) cap_l = 0;
    if (cap_l > N_TOK) cap_l = N_TOK;
    int cap = (int)cap_l;

    vq_prep<<<1, 1, 0, stream>>>(loss_acc, cnt);
    vq_main<<<N_TOK / MTILE, 256, 0, stream>>>(z, emb, out_q, out_idx,
                                               loss_acc, cnt, list, cap);
    vq_refine<<<1024, 256, 0, stream>>>(z, emb, out_q, out_idx, cnt, list, cap);
    vq_final<<<1, 1, 0, stream>>>(loss_acc, out_loss);
}

// Round 2
// 867.355 us; speedup vs baseline: 6.1694x; 3.8048x over previous
//
#include <hip/hip_runtime.h>

#define N_TOK 524288
#define DIM 128
#define NCODE 512
#define TAU 1e-4f

typedef __attribute__((ext_vector_type(8))) short short8;
typedef __attribute__((ext_vector_type(4))) float f32x4;

// ws layout:
// [0,8)      double loss_acc
// [8,12)     int cnt
// [2048,4096)    float enorm[512]  (np_sumsq128-exact ||e||^2)
// [4096,266240)  bf16 hi/lo emb granules: [pass8][kg32][n64][8 bf16]
//                kg<16: hi of k=kg*8..+7 ; kg>=16: lo of k=(kg-16)*8..+7
// [266240,...)   int list[cap]
#define WS_EMB_OFF 4096
#define WS_LIST_OFF 266240

// ---------- numpy-exact helpers (unchanged from verified rounds) ----------
__device__ __forceinline__ float np_sumsq128(const float* __restrict__ p) {
#pragma clang fp contract(off)
    float r[8];
#pragma unroll
    for (int j = 0; j < 8; ++j) { float v = p[j]; r[j] = v * v; }
#pragma unroll
    for (int i = 8; i < 128; i += 8) {
#pragma unroll
        for (int j = 0; j < 8; ++j) { float v = p[i + j]; r[j] = r[j] + v * v; }
    }
    return ((r[0] + r[1]) + (r[2] + r[3])) + ((r[4] + r[5]) + (r[6] + r[7]));
}

__device__ __forceinline__ float seq_dot128(const float* __restrict__ a,
                                            const float* __restrict__ b) {
    float acc = 0.f;
#pragma unroll
    for (int d = 0; d < DIM; ++d) acc = __builtin_fmaf(a[d], b[d], acc);
    return acc;
}

// Full numpy-fp32 emulation over all codes (cold fallback when list overflows).
__device__ __attribute__((noinline)) int np_argmin_token(
    const float* __restrict__ zrow, const float* __restrict__ emb) {
    float zn = np_sumsq128(zrow);
    float bd = 1e30f; int bk = 0;
    for (int k = 0; k < NCODE; ++k) {
        const float* e = emb + (size_t)k * DIM;
        float en = np_sumsq128(e);
        float dot = seq_dot128(zrow, e);
        float t = zn + en;
        float c = t - 2.0f * dot;
        if (c < bd) { bd = c; bk = k; }
    }
    return bk;
}

// ---------- bf16 split helpers ----------
__device__ __forceinline__ unsigned short f2bf(float x) {
    unsigned u = __float_as_uint(x);
    unsigned r = (u + 0x7FFFu + ((u >> 16) & 1u)) >> 16;   // RN-even
    return (unsigned short)r;
}
__device__ __forceinline__ float bf2f(unsigned short h) {
    return __uint_as_float(((unsigned)h) << 16);
}

__device__ __forceinline__ f32x4 mfma16(short8 a, short8 b, f32x4 c) {
    return __builtin_amdgcn_mfma_f32_16x16x32_bf16(a, b, c, 0, 0, 0);
}

// ---------- prep: zero accumulators, enorm, emb hi/lo granules ----------
__global__ void vq_prep(const float* __restrict__ emb, float* __restrict__ enorm,
                        unsigned short* __restrict__ embws,
                        double* loss_acc, int* cnt)
{
    int n = blockIdx.x * 256 + threadIdx.x;   // 0..511
    if (n == 0) { *loss_acc = 0.0; *cnt = 0; }
    const float* e = emb + (size_t)n * DIM;
    enorm[n] = np_sumsq128(e);
    int p = n >> 6, nl = n & 63;
    for (int kg = 0; kg < 16; ++kg) {
        size_t gh = ((size_t)((p * 32 + kg) * 64 + nl)) * 8;
        size_t gl = ((size_t)((p * 32 + kg + 16) * 64 + nl)) * 8;
#pragma unroll
        for (int j = 0; j < 8; ++j) {
            float v = e[kg * 8 + j];
            unsigned short h = f2bf(v);
            embws[gh + j] = h;
            embws[gl + j] = f2bf(v - bf2f(h));
        }
    }
}

// ---------- main: MFMA split-bf16 distances + fused argmin ----------
__global__ __launch_bounds__(256, 2) void vq_main(
    const float* __restrict__ z, const float* __restrict__ emb,
    const unsigned short* __restrict__ embws, const float* __restrict__ enorm,
    float* __restrict__ out_q, float* __restrict__ out_idx,
    double* __restrict__ loss_acc, int* __restrict__ cnt,
    int* __restrict__ list, int cap)
{
    __shared__ __align__(16) unsigned short s_b[32 * 64 * 8];  // 32 KB: one 64-code pass
    __shared__ float s_en[NCODE];
    __shared__ float s_gap[128];
    __shared__ int s_bk[128];

    const int tid = threadIdx.x;
    const int w = tid >> 6;        // wave: tokens w*32..w*32+31
    const int l = tid & 63;
    const int g = l >> 4;          // k-group
    const int c16 = l & 15;        // tile column (code) / tile row (token) index
    const size_t blockRow = (size_t)blockIdx.x * 128;

    s_en[tid] = enorm[tid];
    s_en[tid + 256] = enorm[tid + 256];

    // z fragments: 2 M-tiles x 4 k-steps, split into bf16 hi/lo (kept in regs)
    short8 a_hi[2][4], a_lo[2][4];
#pragma unroll
    for (int mt = 0; mt < 2; ++mt) {
#pragma unroll
        for (int ks = 0; ks < 4; ++ks) {
            const float* src = z + (blockRow + w * 32 + mt * 16 + c16) * DIM
                                 + ks * 32 + g * 8;
            float4 v0 = *(const float4*)src;
            float4 v1 = *(const float4*)(src + 4);
            float vv[8] = {v0.x, v0.y, v0.z, v0.w, v1.x, v1.y, v1.z, v1.w};
#pragma unroll
            for (int j = 0; j < 8; ++j) {
                unsigned short h = f2bf(vv[j]);
                a_hi[mt][ks][j] = (short)h;
                a_lo[mt][ks][j] = (short)f2bf(vv[j] - bf2f(h));
            }
        }
    }

    float m1[8], m2[8]; int bk[8];
#pragma unroll
    for (int s = 0; s < 8; ++s) { m1[s] = 1e30f; m2[s] = 1e30f; bk[s] = 0; }

    const float4* ews = (const float4*)embws;   // 16B granules
    float4* sb4 = (float4*)s_b;
    const short8* sb8 = (const short8*)s_b;
    const f32x4 fzero = {0.f, 0.f, 0.f, 0.f};

    for (int p = 0; p < 8; ++p) {               // 64 codes per pass
        if (p) __syncthreads();                 // everyone done reading s_b
        // stage 32 KB (pre-converted, already in frag granule order)
#pragma unroll
        for (int j = 0; j < 8; ++j)
            sb4[j * 256 + tid] = ews[p * 2048 + j * 256 + tid];
        __syncthreads();

        f32x4 acc[2][4];
#pragma unroll
        for (int mt = 0; mt < 2; ++mt)
#pragma unroll
            for (int nt = 0; nt < 4; ++nt) acc[mt][nt] = fzero;

        // k̂-steps: ks<4 -> b_hi region (pairs a_hi AND a_lo); ks>=4 -> b_lo (a_hi)
#pragma unroll
        for (int ks = 0; ks < 8; ++ks) {
            const int kgb = (ks * 4 + g) * 64;
#pragma unroll
            for (int nt = 0; nt < 4; ++nt) {
                short8 b = sb8[kgb + nt * 16 + c16];
                if (ks < 4) {
                    acc[0][nt] = mfma16(a_hi[0][ks], b, acc[0][nt]);
                    acc[1][nt] = mfma16(a_hi[1][ks], b, acc[1][nt]);
                    acc[0][nt] = mfma16(a_lo[0][ks], b, acc[0][nt]);
                    acc[1][nt] = mfma16(a_lo[1][ks], b, acc[1][nt]);
                } else {
                    acc[0][nt] = mfma16(a_hi[0][ks - 4], b, acc[0][nt]);
                    acc[1][nt] = mfma16(a_hi[1][ks - 4], b, acc[1][nt]);
                }
            }
        }

        // fold this pass into per-token running top-2 (codes ascending per lane)
#pragma unroll
        for (int nt = 0; nt < 4; ++nt) {
            int kc = p * 64 + nt * 16 + c16;
            float en = s_en[kc];
#pragma unroll
            for (int mt = 0; mt < 2; ++mt)
#pragma unroll
                for (int r = 0; r < 4; ++r) {
                    int s = mt * 4 + r;
                    float d = fmaf(-2.0f, acc[mt][nt][r], en);
                    if (d < m1[s]) { m2[s] = m1[s]; m1[s] = d; bk[s] = kc; }
                    else if (d < m2[s]) { m2[s] = d; }
                }
        }
    }

    // cross-lane top-2 merge within each 16-lane row group (lowest-k tie-break)
#pragma unroll
    for (int s = 0; s < 8; ++s) {
#pragma unroll
        for (int off = 1; off < 16; off <<= 1) {
            float b1 = __shfl_xor(m1[s], off);
            float b2 = __shfl_xor(m2[s], off);
            int bko = __shfl_xor(bk[s], off);
            float nm2 = fminf(fminf(m2[s], b2), fmaxf(m1[s], b1));
            if (b1 < m1[s] || (b1 == m1[s] && bko < bk[s])) { m1[s] = b1; bk[s] = bko; }
            m2[s] = nm2;
        }
    }
    if (c16 == 0) {
#pragma unroll
        for (int s = 0; s < 8; ++s) {
            int t = w * 32 + (s >> 2) * 16 + g * 4 + (s & 3);
            s_gap[t] = m2[s] - m1[s];
            s_bk[t] = bk[s];
        }
    }
    __syncthreads();

    // epilogue: one thread per token (proven round-1 tail, z re-read from L2)
    double sd = 0.0;
    if (tid < 128) {
        size_t n = blockRow + (size_t)tid;
        int best = s_bk[tid];
        if (s_gap[tid] < TAU) {
            int pos = atomicAdd(cnt, 1);
            if (pos < cap) {
                list[pos] = (int)n;                 // refined by vq_refine
            } else {
                best = np_argmin_token(z + n * DIM, emb);
            }
        }
        const float4* eb = (const float4*)(emb + (size_t)best * DIM);
        const float4* zr4 = (const float4*)(z + n * DIM);
        float4* oq = (float4*)(out_q + n * DIM);
        float sx = 0.f, sy = 0.f, szz = 0.f, sw = 0.f;
#pragma unroll
        for (int j = 0; j < DIM / 4; ++j) {
            float4 e = eb[j];
            float4 zz = zr4[j];
            float dx = e.x - zz.x, dy = e.y - zz.y, dz = e.z - zz.z, dw = e.w - zz.w;
            float4 o; o.x = zz.x + dx; o.y = zz.y + dy; o.z = zz.z + dz; o.w = zz.w + dw;
            oq[j] = o;
            sx = fmaf(dx, dx, sx); sy = fmaf(dy, dy, sy);
            szz = fmaf(dz, dz, szz); sw = fmaf(dw, dw, sw);
        }
        out_idx[n] = (float)best;
        sd = (double)((sx + sy) + (szz + sw));
    }
#pragma unroll
    for (int off = 32; off > 0; off >>= 1) sd += __shfl_down(sd, off);
    if (l == 0 && sd != 0.0) atomicAdd(loss_acc, sd);
}

// ---------- refine: batched 8 tokens/block, numpy-fp32 exact ----------
__global__ __launch_bounds__(256) void vq_refine(
    const float* __restrict__ z, const float* __restrict__ emb,
    const float* __restrict__ enorm,
    float* __restrict__ out_q, float* __restrict__ out_idx,
    const int* __restrict__ cnt, const int* __restrict__ list, int cap)
{
    __shared__ __align__(16) float s_z[8][DIM];
    __shared__ float s_zn[8];
    __shared__ int s_list[8];
    __shared__ float s_pd[4][8];
    __shared__ int s_pk[4][8];
    __shared__ int s_best[8];

    int nwork = *cnt;
    if (nwork > cap) nwork = cap;
    const int tid = threadIdx.x;
    const int w = tid >> 6, l = tid & 63;

    for (int i0 = blockIdx.x * 8; i0 < nwork; i0 += gridDim.x * 8) {
        int t = nwork - i0; if (t > 8) t = 8;
        if (tid < 8) s_list[tid] = list[i0 + (tid < t ? tid : 0)];
        __syncthreads();
        for (int idx = tid; idx < 8 * DIM; idx += 256)
            s_z[idx >> 7][idx & 127] = z[(size_t)s_list[idx >> 7] * DIM + (idx & 127)];
        __syncthreads();
        if (tid < 8) s_zn[tid] = np_sumsq128(&s_z[tid][0]);
        __syncthreads();

        const int k0 = tid, k1 = tid + 256;
        const float en0 = enorm[k0], en1 = enorm[k1];
        const float4* e0v = (const float4*)(emb + (size_t)k0 * DIM);
        const float4* e1v = (const float4*)(emb + (size_t)k1 * DIM);
        float acc0[8], acc1[8];
#pragma unroll
        for (int j = 0; j < 8; ++j) { acc0[j] = 0.f; acc1[j] = 0.f; }

        for (int db = 0; db < 8; ++db) {       // d ascending => seq_dot128-exact
            float ef0[16], ef1[16];
#pragma unroll
            for (int q = 0; q < 4; ++q) {
                float4 a = e0v[db * 4 + q];
                float4 b = e1v[db * 4 + q];
                ef0[q * 4] = a.x; ef0[q * 4 + 1] = a.y; ef0[q * 4 + 2] = a.z; ef0[q * 4 + 3] = a.w;
                ef1[q * 4] = b.x; ef1[q * 4 + 1] = b.y; ef1[q * 4 + 2] = b.z; ef1[q * 4 + 3] = b.w;
            }
#pragma unroll
            for (int j = 0; j < 8; ++j) {
                float zv[16];
#pragma unroll
                for (int q = 0; q < 4; ++q) {
                    float4 zt = *(const float4*)&s_z[j][db * 16 + q * 4];
                    zv[q * 4] = zt.x; zv[q * 4 + 1] = zt.y; zv[q * 4 + 2] = zt.z; zv[q * 4 + 3] = zt.w;
                }
#pragma unroll
                for (int dd = 0; dd < 16; ++dd)
                    acc0[j] = __builtin_fmaf(zv[dd], ef0[dd], acc0[j]);
#pragma unroll
                for (int dd = 0; dd < 16; ++dd)
                    acc1[j] = __builtin_fmaf(zv[dd], ef1[dd], acc1[j]);
            }
        }

        float bd[8]; int bkk[8];
#pragma unroll
        for (int j = 0; j < 8; ++j) {
            float c0 = (s_zn[j] + en0) - 2.0f * acc0[j];
            float c1 = (s_zn[j] + en1) - 2.0f * acc1[j];
            bd[j] = c0; bkk[j] = k0;
            if (c1 < c0) { bd[j] = c1; bkk[j] = k1; }   // k0<k1: strict <
        }
#pragma unroll
        for (int j = 0; j < 8; ++j) {
#pragma unroll
            for (int off = 1; off < 64; off <<= 1) {
                float od = __shfl_xor(bd[j], off);
                int ok = __shfl_xor(bkk[j], off);
                if (od < bd[j] || (od == bd[j] && ok < bkk[j])) { bd[j] = od; bkk[j] = ok; }
            }
        }
        if (l == 0) {
#pragma unroll
            for (int j = 0; j < 8; ++j) { s_pd[w][j] = bd[j]; s_pk[w][j] = bkk[j]; }
        }
        __syncthreads();
        if (tid < 8) {
            float d = s_pd[0][tid]; int k = s_pk[0][tid];
#pragma unroll
            for (int ww = 1; ww < 4; ++ww) {
                float od = s_pd[ww][tid]; int ok = s_pk[ww][tid];
                if (od < d || (od == d && ok < k)) { d = od; k = ok; }
            }
            s_best[tid] = k;
            if (tid < t) out_idx[(size_t)s_list[tid]] = (float)k;
        }
        __syncthreads();
        for (int idx = tid; idx < t * DIM; idx += 256) {
            int j = idx >> 7, d = idx & 127;
            size_t n = (size_t)s_list[j];
            float zz = s_z[j][d];
            float e = emb[(size_t)s_best[j] * DIM + d];
            out_q[n * DIM + d] = zz + (e - zz);
        }
        __syncthreads();
    }
}

__global__ void vq_final(const double* __restrict__ loss_acc, float* __restrict__ out_loss) {
    double m = *loss_acc / ((double)N_TOK * (double)DIM);
    *out_loss = (float)(1.25 * m);
}

extern "C" void kernel_launch(void* const* d_in, const int* in_sizes, int n_in,
                              void* d_out, int out_size, void* d_ws, size_t ws_size,
                              hipStream_t stream) {
    const float* z = (const float*)d_in[0];
    const float* emb = (const float*)d_in[1];
    float* out_q = (float*)d_out;
    float* out_loss = out_q + (size_t)N_TOK * DIM;
    float* out_idx = out_loss + 1;

    char* ws = (char*)d_ws;
    double* loss_acc = (double*)ws;
    int* cnt = (int*)(ws + 8);
    float* enorm = (float*)(ws + 2048);
    unsigned short* embws = (unsigned short*)(ws + WS_EMB_OFF);
    int* list = (int*)(ws + WS_LIST_OFF);
    long cap_l = ((long)ws_size - WS_LIST_OFF) / 4;
    if (cap_l < 0) cap_l = 0;
    if (cap_l > N_TOK) cap_l = N_TOK;
    int cap = (int)cap_l;

    vq_prep<<<2, 256, 0, stream>>>(emb, enorm, embws, loss_acc, cnt);
    vq_main<<<N_TOK / 128, 256, 0, stream>>>(z, emb, embws, enorm, out_q, out_idx,
                                             loss_acc, cnt, list, cap);
    vq_refine<<<1024, 256, 0, stream>>>(z, emb, enorm, out_q, out_idx, cnt, list, cap);
    vq_final<<<1, 1, 0, stream>>>(loss_acc, out_loss);
}